// Round 1
// baseline (69.891 us; speedup 1.0000x reference)
//
#include <hip/hip_runtime.h>

#define MT_EPS 1e-8f

// Per-triangle precompute: fold f=1/det, v1 offset, and validity into
// affine coefficients so the hot loop is 7 FMAs + compares per test.
// Layout per triangle (3x float4, 48B stride):
//   c0 = (cu_x, cu_y, cu_0, cv_x)
//   c1 = (cv_y, cv_0, ct_x, ct_y)
//   c2 = (ct_z, ct_0, 0, 0)
__global__ __launch_bounds__(256) void mt_precompute(
    const float* __restrict__ v1, const float* __restrict__ v2,
    const float* __restrict__ v3, float4* __restrict__ coef, int F)
{
    int f = blockIdx.x * 256 + threadIdx.x;
    if (f >= F) return;
    float v1x = v1[3*f+0], v1y = v1[3*f+1], v1z = v1[3*f+2];
    float v2x = v2[3*f+0], v2y = v2[3*f+1], v2z = v2[3*f+2];
    float v3x = v3[3*f+0], v3y = v3[3*f+1], v3z = v3[3*f+2];
    float e1x = v2x - v1x, e1y = v2y - v1y, e1z = v2z - v1z;
    float e2x = v3x - v1x, e2y = v3y - v1y, e2z = v3z - v1z;
    // h = cross(d, e2), d=(0,0,1) -> (-e2y, e2x, 0)
    float hx = -e2y, hy = e2x;
    float a = e1x * hx + e1y * hy;                 // determinant
    float fi = (fabsf(a) > MT_EPS) ? (1.0f / a) : 0.0f;  // invalid -> 0 (kills hit via t>EPS)
    // u = fi * dot(p - v1, h)  (h_z = 0)
    float cux = fi * hx, cuy = fi * hy;
    float cu0 = -(v1x * cux + v1y * cuy);
    // v = fi * (s_x*e1y - s_y*e1x)
    float cvx = fi * e1y, cvy = -fi * e1x;
    float cv0 = -(v1x * cvx + v1y * cvy);
    // t = fi * dot(s, cross(e1, e2))
    float nx = e1y * e2z - e1z * e2y;
    float ny = e1z * e2x - e1x * e2z;
    float nz = e1x * e2y - e1y * e2x;
    float ctx = fi * nx, cty = fi * ny, ctz = fi * nz;
    float ct0 = -(v1x * ctx + v1y * cty + v1z * ctz);
    coef[3*f+0] = make_float4(cux, cuy, cu0, cvx);
    coef[3*f+1] = make_float4(cvy, cv0, ctx, cty);
    coef[3*f+2] = make_float4(ctz, ct0, 0.0f, 0.0f);
}

// One thread per point; triangles split across blockIdx.y for occupancy.
// Coefficient index is wave-uniform -> scalar loads (s_load_dwordx4),
// keeping the VALU free for the 7 FMA + 6 cmp/sel per test.
__global__ __launch_bounds__(256) void mt_count(
    const float4* __restrict__ coef, const float* __restrict__ pts,
    float* __restrict__ out, int npts, int F, int tchunk)
{
    int p = blockIdx.x * 256 + threadIdx.x;
    if (p >= npts) return;
    float px = pts[3*p+0];
    float py = pts[3*p+1];
    float pz = pts[3*p+2];
    int fbase = blockIdx.y * tchunk;
    int fend  = fbase + tchunk;
    if (fend > F) fend = F;
    float cnt = 0.0f;
    #pragma unroll 4
    for (int f = fbase; f < fend; ++f) {
        float4 c0 = coef[3*f+0];
        float4 c1 = coef[3*f+1];
        float4 c2 = coef[3*f+2];
        float u = fmaf(c0.x, px, fmaf(c0.y, py, c0.z));
        float v = fmaf(c0.w, px, fmaf(c1.x, py, c1.y));
        float t = fmaf(c1.z, px, fmaf(c1.w, py, fmaf(c2.x, pz, c2.y)));
        float w = u + v;
        // u<=1 is implied by (v>=0 & u+v<=1) under monotone fp rounding.
        bool hit = (fminf(u, v) >= 0.0f) & (w <= 1.0f) & (t > MT_EPS);
        cnt += hit ? 1.0f : 0.0f;
    }
    atomicAdd(&out[p], cnt);  // integer-valued fp adds: order-independent exact
}

extern "C" void kernel_launch(void* const* d_in, const int* in_sizes, int n_in,
                              void* d_out, int out_size, void* d_ws, size_t ws_size,
                              hipStream_t stream) {
    const float* pts = (const float*)d_in[0];   // [B,N,3]
    const float* v1  = (const float*)d_in[1];   // [F,3]
    const float* v2  = (const float*)d_in[2];
    const float* v3  = (const float*)d_in[3];
    float* out = (float*)d_out;                  // [B,N] counts
    int npts = in_sizes[0] / 3;                  // 65536
    int F    = in_sizes[1] / 3;                  // 2048

    float4* coef = (float4*)d_ws;                // 3*F float4 = 96 KB

    // Output must be zeroed every call (harness poisons once, atomics accumulate).
    hipMemsetAsync(d_out, 0, (size_t)out_size * sizeof(float), stream);

    mt_precompute<<<dim3((F + 255) / 256), dim3(256), 0, stream>>>(v1, v2, v3, coef, F);

    const int tsplit = 8;                        // 2048 blocks -> 8 blocks/CU
    int tchunk = (F + tsplit - 1) / tsplit;      // 256 triangles per chunk
    dim3 grid((npts + 255) / 256, tsplit);
    mt_count<<<grid, dim3(256), 0, stream>>>(coef, pts, out, npts, F, tchunk);
}

// Round 2
// 65.593 us; speedup vs baseline: 1.0655x; 1.0655x over previous
//
#include <hip/hip_runtime.h>

#define MT_EPS 1e-8f

// Per-triangle precompute: fold f=1/det, v1 offset, and validity into
// affine coefficients so the hot loop is 7 FMAs + compares per test.
// Layout per triangle (3x float4, 48B stride):
//   c0 = (cu_x, cu_y, cu_0, cv_x)
//   c1 = (cv_y, cv_0, ct_x, ct_y)
//   c2 = (ct_z, ct_0, 0, 0)
__global__ __launch_bounds__(256) void mt_precompute(
    const float* __restrict__ v1, const float* __restrict__ v2,
    const float* __restrict__ v3, float4* __restrict__ coef, int F)
{
    int f = blockIdx.x * 256 + threadIdx.x;
    if (f >= F) return;
    float v1x = v1[3*f+0], v1y = v1[3*f+1], v1z = v1[3*f+2];
    float v2x = v2[3*f+0], v2y = v2[3*f+1], v2z = v2[3*f+2];
    float v3x = v3[3*f+0], v3y = v3[3*f+1], v3z = v3[3*f+2];
    float e1x = v2x - v1x, e1y = v2y - v1y, e1z = v2z - v1z;
    float e2x = v3x - v1x, e2y = v3y - v1y, e2z = v3z - v1z;
    // h = cross(d, e2), d=(0,0,1) -> (-e2y, e2x, 0)
    float hx = -e2y, hy = e2x;
    float a = e1x * hx + e1y * hy;                 // determinant
    float fi = (fabsf(a) > MT_EPS) ? (1.0f / a) : 0.0f;  // invalid -> 0 (kills hit via t>EPS)
    // u = fi * dot(p - v1, h)  (h_z = 0)
    float cux = fi * hx, cuy = fi * hy;
    float cu0 = -(v1x * cux + v1y * cuy);
    // v = fi * (s_x*e1y - s_y*e1x)
    float cvx = fi * e1y, cvy = -fi * e1x;
    float cv0 = -(v1x * cvx + v1y * cvy);
    // t = fi * dot(s, cross(e1, e2))
    float nx = e1y * e2z - e1z * e2y;
    float ny = e1z * e2x - e1x * e2z;
    float nz = e1x * e2y - e1y * e2x;
    float ctx = fi * nx, cty = fi * ny, ctz = fi * nz;
    float ct0 = -(v1x * ctx + v1y * cty + v1z * ctz);
    coef[3*f+0] = make_float4(cux, cuy, cu0, cvx);
    coef[3*f+1] = make_float4(cvy, cv0, ctx, cty);
    coef[3*f+2] = make_float4(ctz, ct0, 0.0f, 0.0f);
}

// 4 points per thread: one wave-uniform 48B coefficient fetch feeds
// 4x14 = 56 VALU ops (4x better scalar-fetch amortization than 1 pt/thread)
// and provides 4 independent FMA chains for ILP. Triangles split across
// blockIdx.y; partial counts merged with atomicAdd (integer-valued fp adds
// are order-independent exact).
__global__ __launch_bounds__(256) void mt_count4(
    const float4* __restrict__ coef, const float* __restrict__ pts,
    float* __restrict__ out, int npts, int F, int tchunk)
{
    int tid = blockIdx.x * 256 + threadIdx.x;
    int p0 = tid * 4;
    if (p0 >= npts) return;
    // 4 consecutive points = 12 floats = 3 coalesced float4 loads
    const float4* pv = (const float4*)(pts + (size_t)p0 * 3);
    float4 a = pv[0], b = pv[1], c = pv[2];
    float px0 = a.x, py0 = a.y, pz0 = a.z;
    float px1 = a.w, py1 = b.x, pz1 = b.y;
    float px2 = b.z, py2 = b.w, pz2 = c.x;
    float px3 = c.y, py3 = c.z, pz3 = c.w;

    int fbase = blockIdx.y * tchunk;
    int fend  = fbase + tchunk;
    if (fend > F) fend = F;

    float cnt0 = 0.0f, cnt1 = 0.0f, cnt2 = 0.0f, cnt3 = 0.0f;
    #pragma unroll 2
    for (int f = fbase; f < fend; ++f) {
        float4 c0 = coef[3*f+0];   // wave-uniform -> s_load_dwordx4
        float4 c1 = coef[3*f+1];
        float4 c2 = coef[3*f+2];

        {
            float u = fmaf(c0.x, px0, fmaf(c0.y, py0, c0.z));
            float v = fmaf(c0.w, px0, fmaf(c1.x, py0, c1.y));
            float t = fmaf(c1.z, px0, fmaf(c1.w, py0, fmaf(c2.x, pz0, c2.y)));
            float w = u + v;
            bool hit = (fminf(u, v) >= 0.0f) & (w <= 1.0f) & (t > MT_EPS);
            cnt0 += hit ? 1.0f : 0.0f;
        }
        {
            float u = fmaf(c0.x, px1, fmaf(c0.y, py1, c0.z));
            float v = fmaf(c0.w, px1, fmaf(c1.x, py1, c1.y));
            float t = fmaf(c1.z, px1, fmaf(c1.w, py1, fmaf(c2.x, pz1, c2.y)));
            float w = u + v;
            bool hit = (fminf(u, v) >= 0.0f) & (w <= 1.0f) & (t > MT_EPS);
            cnt1 += hit ? 1.0f : 0.0f;
        }
        {
            float u = fmaf(c0.x, px2, fmaf(c0.y, py2, c0.z));
            float v = fmaf(c0.w, px2, fmaf(c1.x, py2, c1.y));
            float t = fmaf(c1.z, px2, fmaf(c1.w, py2, fmaf(c2.x, pz2, c2.y)));
            float w = u + v;
            bool hit = (fminf(u, v) >= 0.0f) & (w <= 1.0f) & (t > MT_EPS);
            cnt2 += hit ? 1.0f : 0.0f;
        }
        {
            float u = fmaf(c0.x, px3, fmaf(c0.y, py3, c0.z));
            float v = fmaf(c0.w, px3, fmaf(c1.x, py3, c1.y));
            float t = fmaf(c1.z, px3, fmaf(c1.w, py3, fmaf(c2.x, pz3, c2.y)));
            float w = u + v;
            bool hit = (fminf(u, v) >= 0.0f) & (w <= 1.0f) & (t > MT_EPS);
            cnt3 += hit ? 1.0f : 0.0f;
        }
    }
    atomicAdd(&out[p0+0], cnt0);
    atomicAdd(&out[p0+1], cnt1);
    atomicAdd(&out[p0+2], cnt2);
    atomicAdd(&out[p0+3], cnt3);
}

extern "C" void kernel_launch(void* const* d_in, const int* in_sizes, int n_in,
                              void* d_out, int out_size, void* d_ws, size_t ws_size,
                              hipStream_t stream) {
    const float* pts = (const float*)d_in[0];   // [B,N,3]
    const float* v1  = (const float*)d_in[1];   // [F,3]
    const float* v2  = (const float*)d_in[2];
    const float* v3  = (const float*)d_in[3];
    float* out = (float*)d_out;                  // [B,N] counts
    int npts = in_sizes[0] / 3;                  // 65536
    int F    = in_sizes[1] / 3;                  // 2048

    float4* coef = (float4*)d_ws;                // 3*F float4 = 96 KB

    // Output must be zeroed every call (harness poisons once, atomics accumulate).
    hipMemsetAsync(d_out, 0, (size_t)out_size * sizeof(float), stream);

    mt_precompute<<<dim3((F + 255) / 256), dim3(256), 0, stream>>>(v1, v2, v3, coef, F);

    const int tsplit = 16;                       // 64 x 16 = 1024 blocks -> 4 wg/CU, ILP=4 covers
    int tchunk = (F + tsplit - 1) / tsplit;      // 128 triangles per chunk
    int nthreads = (npts + 3) / 4;               // 16384 threads, 4 points each
    dim3 grid((nthreads + 255) / 256, tsplit);
    mt_count4<<<grid, dim3(256), 0, stream>>>(coef, pts, out, npts, F, tchunk);
}

// Round 3
// 61.202 us; speedup vs baseline: 1.1420x; 1.0717x over previous
//
#include <hip/hip_runtime.h>

#define MT_EPS 1e-8f

// Per-triangle precompute: fold f=1/det, v1 offset, validity, and EPS into
// affine coefficients. Four independent affine forms per test:
//   u   = cu . (px,py,1)
//   v   = cv . (px,py,1)
//   omw = 1-u-v = cw . (px,py,1)      (removes u,v->w dependency chain)
//   tm  = t-EPS = ct . (px,py,pz,1)   (EPS folded: hit test is tm >= 0)
// Layout per triangle (4x float4, 64B stride):
//   c0 = (cu_x, cu_y, cu_0, cv_x)
//   c1 = (cv_y, cv_0, cw_x, cw_y)
//   c2 = (cw_0, ct_x, ct_y, ct_z)
//   c3 = (ct_0 - EPS, 0, 0, 0)
__global__ __launch_bounds__(256) void mt_precompute(
    const float* __restrict__ v1, const float* __restrict__ v2,
    const float* __restrict__ v3, float4* __restrict__ coef, int F)
{
    int f = blockIdx.x * 256 + threadIdx.x;
    if (f >= F) return;
    float v1x = v1[3*f+0], v1y = v1[3*f+1], v1z = v1[3*f+2];
    float v2x = v2[3*f+0], v2y = v2[3*f+1], v2z = v2[3*f+2];
    float v3x = v3[3*f+0], v3y = v3[3*f+1], v3z = v3[3*f+2];
    float e1x = v2x - v1x, e1y = v2y - v1y, e1z = v2z - v1z;
    float e2x = v3x - v1x, e2y = v3y - v1y, e2z = v3z - v1z;
    // h = cross(d, e2), d=(0,0,1) -> (-e2y, e2x, 0)
    float hx = -e2y, hy = e2x;
    float a = e1x * hx + e1y * hy;                 // determinant
    float fi = (fabsf(a) > MT_EPS) ? (1.0f / a) : 0.0f;  // invalid -> all-zero coefs -> tm=-EPS -> no hit
    // u = fi * dot(p - v1, h)  (h_z = 0)
    float cux = fi * hx, cuy = fi * hy;
    float cu0 = -(v1x * cux + v1y * cuy);
    // v = fi * (s_x*e1y - s_y*e1x)
    float cvx = fi * e1y, cvy = -fi * e1x;
    float cv0 = -(v1x * cvx + v1y * cvy);
    // omw = 1 - u - v
    float cwx = -(cux + cvx), cwy = -(cuy + cvy);
    float cw0 = 1.0f - cu0 - cv0;
    // t = fi * dot(s, cross(e1, e2))
    float nx = e1y * e2z - e1z * e2y;
    float ny = e1z * e2x - e1x * e2z;
    float nz = e1x * e2y - e1y * e2x;
    float ctx = fi * nx, cty = fi * ny, ctz = fi * nz;
    float ct0 = -(v1x * ctx + v1y * cty + v1z * ctz) - MT_EPS;
    coef[4*f+0] = make_float4(cux, cuy, cu0, cvx);
    coef[4*f+1] = make_float4(cvy, cv0, cwx, cwy);
    coef[4*f+2] = make_float4(cw0, ctx, cty, ctz);
    coef[4*f+3] = make_float4(ct0, 0.0f, 0.0f, 0.0f);
}

// 4 points per thread: one wave-uniform 64B coefficient fetch feeds
// 4 x 13 = 52 VALU ops; 4 independent chains for ILP. Per test:
// 9 FMA + v_min3 + v_min + v_cmp + v_addc = 13 VALU.
// tsplit=32 -> 2048 blocks -> 8 blocks/CU -> 32 waves/CU (full cap).
__global__ __launch_bounds__(256) void mt_count4(
    const float4* __restrict__ coef, const float* __restrict__ pts,
    float* __restrict__ out, int npts, int F, int tchunk)
{
    int tid = blockIdx.x * 256 + threadIdx.x;
    int p0 = tid * 4;
    if (p0 >= npts) return;
    // 4 consecutive points = 12 floats = 3 coalesced float4 loads
    const float4* pv = (const float4*)(pts + (size_t)p0 * 3);
    float4 a = pv[0], b = pv[1], c = pv[2];
    float px0 = a.x, py0 = a.y, pz0 = a.z;
    float px1 = a.w, py1 = b.x, pz1 = b.y;
    float px2 = b.z, py2 = b.w, pz2 = c.x;
    float px3 = c.y, py3 = c.z, pz3 = c.w;

    int fbase = blockIdx.y * tchunk;
    int fend  = fbase + tchunk;
    if (fend > F) fend = F;

    int cnt0 = 0, cnt1 = 0, cnt2 = 0, cnt3 = 0;
    #pragma unroll 4
    for (int f = fbase; f < fend; ++f) {
        float4 c0 = coef[4*f+0];   // wave-uniform -> s_load_dwordx4
        float4 c1 = coef[4*f+1];
        float4 c2 = coef[4*f+2];
        float ct0 = coef[4*f+3].x;

        {
            float u = fmaf(c0.x, px0, fmaf(c0.y, py0, c0.z));
            float v = fmaf(c0.w, px0, fmaf(c1.x, py0, c1.y));
            float w = fmaf(c1.z, px0, fmaf(c1.w, py0, c2.x));
            float t = fmaf(c2.y, px0, fmaf(c2.z, py0, fmaf(c2.w, pz0, ct0)));
            float m = fminf(fminf(fminf(u, v), w), t);   // min3 + min
            cnt0 += (m >= 0.0f) ? 1 : 0;                 // v_cmp + v_addc
        }
        {
            float u = fmaf(c0.x, px1, fmaf(c0.y, py1, c0.z));
            float v = fmaf(c0.w, px1, fmaf(c1.x, py1, c1.y));
            float w = fmaf(c1.z, px1, fmaf(c1.w, py1, c2.x));
            float t = fmaf(c2.y, px1, fmaf(c2.z, py1, fmaf(c2.w, pz1, ct0)));
            float m = fminf(fminf(fminf(u, v), w), t);
            cnt1 += (m >= 0.0f) ? 1 : 0;
        }
        {
            float u = fmaf(c0.x, px2, fmaf(c0.y, py2, c0.z));
            float v = fmaf(c0.w, px2, fmaf(c1.x, py2, c1.y));
            float w = fmaf(c1.z, px2, fmaf(c1.w, py2, c2.x));
            float t = fmaf(c2.y, px2, fmaf(c2.z, py2, fmaf(c2.w, pz2, ct0)));
            float m = fminf(fminf(fminf(u, v), w), t);
            cnt2 += (m >= 0.0f) ? 1 : 0;
        }
        {
            float u = fmaf(c0.x, px3, fmaf(c0.y, py3, c0.z));
            float v = fmaf(c0.w, px3, fmaf(c1.x, py3, c1.y));
            float w = fmaf(c1.z, px3, fmaf(c1.w, py3, c2.x));
            float t = fmaf(c2.y, px3, fmaf(c2.z, py3, fmaf(c2.w, pz3, ct0)));
            float m = fminf(fminf(fminf(u, v), w), t);
            cnt3 += (m >= 0.0f) ? 1 : 0;
        }
    }
    atomicAdd(&out[p0+0], (float)cnt0);   // integer-valued fp adds: exact
    atomicAdd(&out[p0+1], (float)cnt1);
    atomicAdd(&out[p0+2], (float)cnt2);
    atomicAdd(&out[p0+3], (float)cnt3);
}

extern "C" void kernel_launch(void* const* d_in, const int* in_sizes, int n_in,
                              void* d_out, int out_size, void* d_ws, size_t ws_size,
                              hipStream_t stream) {
    const float* pts = (const float*)d_in[0];   // [B,N,3]
    const float* v1  = (const float*)d_in[1];   // [F,3]
    const float* v2  = (const float*)d_in[2];
    const float* v3  = (const float*)d_in[3];
    float* out = (float*)d_out;                  // [B,N] counts
    int npts = in_sizes[0] / 3;                  // 65536
    int F    = in_sizes[1] / 3;                  // 2048

    float4* coef = (float4*)d_ws;                // 4*F float4 = 128 KB

    // Output must be zeroed every call (harness poisons once, atomics accumulate).
    hipMemsetAsync(d_out, 0, (size_t)out_size * sizeof(float), stream);

    mt_precompute<<<dim3((F + 255) / 256), dim3(256), 0, stream>>>(v1, v2, v3, coef, F);

    const int tsplit = 32;                       // 64 x 32 = 2048 blocks -> 8 wg/CU -> 32 waves/CU
    int tchunk = (F + tsplit - 1) / tsplit;      // 64 triangles per chunk
    int nthreads = (npts + 3) / 4;               // 16384 threads, 4 points each
    dim3 grid((nthreads + 255) / 256, tsplit);
    mt_count4<<<grid, dim3(256), 0, stream>>>(coef, pts, out, npts, F, tchunk);
}

// Round 4
// 53.874 us; speedup vs baseline: 1.2973x; 1.1360x over previous
//
#include <hip/hip_runtime.h>

#define MT_EPS 1e-8f
#define TCHUNK 64   // triangles per block chunk (LDS-staged)

// Per-triangle precompute: fold f=1/det, v1 offset, validity, and EPS into
// 10 affine coefficients (stored padded to 4x float4 = 64B stride):
//   u  = cu . (px,py,1)
//   v  = cv . (px,py,1)
//   tm = t-EPS = ct . (px,py,pz,1)     (hit test: tm >= 0)
//   (1-u-v computed in-kernel as 1-(u+v))
// Layout: c0 = (cu_x, cu_y, cu_0, cv_x)
//         c1 = (cv_y, cv_0, ct_x, ct_y)
//         c2 = (ct_z, ct_0-EPS, -, -)   c3 unused pad
__global__ __launch_bounds__(256) void mt_precompute(
    const float* __restrict__ v1, const float* __restrict__ v2,
    const float* __restrict__ v3, float4* __restrict__ coef, int F)
{
    int f = blockIdx.x * 256 + threadIdx.x;
    if (f >= F) return;
    float v1x = v1[3*f+0], v1y = v1[3*f+1], v1z = v1[3*f+2];
    float v2x = v2[3*f+0], v2y = v2[3*f+1], v2z = v2[3*f+2];
    float v3x = v3[3*f+0], v3y = v3[3*f+1], v3z = v3[3*f+2];
    float e1x = v2x - v1x, e1y = v2y - v1y, e1z = v2z - v1z;
    float e2x = v3x - v1x, e2y = v3y - v1y, e2z = v3z - v1z;
    // h = cross(d, e2), d=(0,0,1) -> (-e2y, e2x, 0)
    float hx = -e2y, hy = e2x;
    float a = e1x * hx + e1y * hy;                       // determinant
    float fi = (fabsf(a) > MT_EPS) ? (1.0f / a) : 0.0f;  // invalid -> zero coefs -> tm=-EPS -> no hit
    float cux = fi * hx, cuy = fi * hy;
    float cu0 = -(v1x * cux + v1y * cuy);
    float cvx = fi * e1y, cvy = -fi * e1x;
    float cv0 = -(v1x * cvx + v1y * cvy);
    float nx = e1y * e2z - e1z * e2y;
    float ny = e1z * e2x - e1x * e2z;
    float nz = e1x * e2y - e1y * e2x;
    float ctx = fi * nx, cty = fi * ny, ctz = fi * nz;
    float ct0 = -(v1x * ctx + v1y * cty + v1z * ctz) - MT_EPS;
    coef[4*f+0] = make_float4(cux, cuy, cu0, cvx);
    coef[4*f+1] = make_float4(cvy, cv0, ctx, cty);
    coef[4*f+2] = make_float4(ctz, ct0, 0.0f, 0.0f);
    // coef[4*f+3] intentionally unwritten (never read by math)
}

// 4 points/thread, TCHUNK triangles per block staged in LDS once
// (cooperative coalesced load + 1 barrier), inner loop reads coefficients
// via wave-uniform ds_read (broadcast, conflict-free, CU-private) --
// removing the per-wave per-iter K$/L2 round trip that capped VALUBusy at 53%.
// Per test: 7 FMA + add + sub + min3 + min + cmp + addc = 13 VALU.
__global__ __launch_bounds__(256) void mt_count4(
    const float4* __restrict__ coef, const float* __restrict__ pts,
    float* __restrict__ out, int npts, int F)
{
    __shared__ float4 scoef[TCHUNK * 4];   // 4 KB, 64B stride per triangle

    int tid = blockIdx.x * 256 + threadIdx.x;
    int p0 = tid * 4;
    bool live = (p0 < npts);

    // Preload this thread's 4 points (3 coalesced float4) before the barrier.
    float px0=0, py0=0, pz0=0, px1=0, py1=0, pz1=0;
    float px2=0, py2=0, pz2=0, px3=0, py3=0, pz3=0;
    if (live) {
        const float4* pv = (const float4*)(pts + (size_t)p0 * 3);
        float4 a = pv[0], b = pv[1], c = pv[2];
        px0 = a.x; py0 = a.y; pz0 = a.z;
        px1 = a.w; py1 = b.x; pz1 = b.y;
        px2 = b.z; py2 = b.w; pz2 = c.x;
        px3 = c.y; py3 = c.z; pz3 = c.w;
    }

    // Stage coefficient chunk: 256 threads x 16B = 4KB, zero-pad past F.
    {
        int gidx = blockIdx.y * (TCHUNK * 4) + threadIdx.x;   // float4 index
        scoef[threadIdx.x] = (gidx < 4 * F) ? coef[gidx]
                                            : make_float4(0.f, 0.f, 0.f, 0.f);
    }
    __syncthreads();

    int cnt0 = 0, cnt1 = 0, cnt2 = 0, cnt3 = 0;
    #pragma unroll 4
    for (int j = 0; j < TCHUNK; ++j) {        // fixed trip count (zero-padded)
        float4 c0 = scoef[4*j+0];             // ds_read_b128, uniform -> broadcast
        float4 c1 = scoef[4*j+1];
        float2 c2 = *(const float2*)&scoef[4*j+2];  // ds_read_b64

        {
            float u = fmaf(c0.x, px0, fmaf(c0.y, py0, c0.z));
            float v = fmaf(c0.w, px0, fmaf(c1.x, py0, c1.y));
            float t = fmaf(c1.z, px0, fmaf(c1.w, py0, fmaf(c2.x, pz0, c2.y)));
            float m = fminf(fminf(fminf(u, v), t), 1.0f - (u + v));
            cnt0 += (m >= 0.0f) ? 1 : 0;
        }
        {
            float u = fmaf(c0.x, px1, fmaf(c0.y, py1, c0.z));
            float v = fmaf(c0.w, px1, fmaf(c1.x, py1, c1.y));
            float t = fmaf(c1.z, px1, fmaf(c1.w, py1, fmaf(c2.x, pz1, c2.y)));
            float m = fminf(fminf(fminf(u, v), t), 1.0f - (u + v));
            cnt1 += (m >= 0.0f) ? 1 : 0;
        }
        {
            float u = fmaf(c0.x, px2, fmaf(c0.y, py2, c0.z));
            float v = fmaf(c0.w, px2, fmaf(c1.x, py2, c1.y));
            float t = fmaf(c1.z, px2, fmaf(c1.w, py2, fmaf(c2.x, pz2, c2.y)));
            float m = fminf(fminf(fminf(u, v), t), 1.0f - (u + v));
            cnt2 += (m >= 0.0f) ? 1 : 0;
        }
        {
            float u = fmaf(c0.x, px3, fmaf(c0.y, py3, c0.z));
            float v = fmaf(c0.w, px3, fmaf(c1.x, py3, c1.y));
            float t = fmaf(c1.z, px3, fmaf(c1.w, py3, fmaf(c2.x, pz3, c2.y)));
            float m = fminf(fminf(fminf(u, v), t), 1.0f - (u + v));
            cnt3 += (m >= 0.0f) ? 1 : 0;
        }
    }
    if (live) {
        atomicAdd(&out[p0+0], (float)cnt0);   // integer-valued fp adds: exact
        atomicAdd(&out[p0+1], (float)cnt1);
        atomicAdd(&out[p0+2], (float)cnt2);
        atomicAdd(&out[p0+3], (float)cnt3);
    }
}

extern "C" void kernel_launch(void* const* d_in, const int* in_sizes, int n_in,
                              void* d_out, int out_size, void* d_ws, size_t ws_size,
                              hipStream_t stream) {
    const float* pts = (const float*)d_in[0];   // [B,N,3]
    const float* v1  = (const float*)d_in[1];   // [F,3]
    const float* v2  = (const float*)d_in[2];
    const float* v3  = (const float*)d_in[3];
    float* out = (float*)d_out;                  // [B,N] counts
    int npts = in_sizes[0] / 3;                  // 65536
    int F    = in_sizes[1] / 3;                  // 2048

    float4* coef = (float4*)d_ws;                // 4*F float4 = 128 KB

    // Output must be zeroed every call (harness poisons once, atomics accumulate).
    hipMemsetAsync(d_out, 0, (size_t)out_size * sizeof(float), stream);

    mt_precompute<<<dim3((F + 255) / 256), dim3(256), 0, stream>>>(v1, v2, v3, coef, F);

    int tsplit = (F + TCHUNK - 1) / TCHUNK;      // 32 -> 64x32 = 2048 blocks, 8/CU
    int nthreads = (npts + 3) / 4;               // 16384 threads, 4 points each
    dim3 grid((nthreads + 255) / 256, tsplit);
    mt_count4<<<grid, dim3(256), 0, stream>>>(coef, pts, out, npts, F);
}